// Round 5
// baseline (85.056 us; speedup 1.0000x reference)
//
#include <hip/hip_runtime.h>
#include <math.h>

#define PP 8192
#define DD 4096
#define NTOT 32768           // B * P
#define K_LOW 29490          // floor(0.9 * (NTOT-1))
#define NBINS 8192           // bucket = bits(|a|) >> 18
#define SCALE 1048576.0f     // 2^20 fixed-point for spmv accumulation
#define INV_SCALE (1.0f / 1048576.0f)
#define MSCALE 262144.0f     // 2^18 fixed-point for mean-sum accumulation
#define INV_MSCALE (1.0f / 262144.0f)
#define LIST_CAP 3072

__device__ __forceinline__ float dot4(float4 w, float4 v) {
  return fmaf(w.x, v.x, fmaf(w.y, v.y, fmaf(w.z, v.z, w.w * v.w)));
}

// ---------------- Kernel 1: a = x @ W^T + b ----------------
// 512 blocks x 256 thr; each wave handles 4 consecutive rows (4 W streams per
// lane for memory-level parallelism, x loads amortized 4x). f64 chunk accum,
// same per-(row,batch) order as before -> bit-identical a.
// Blocks 0-31 zero rec; block 32 zeroes scalar accumulators (consumed only by
// later kernels -> no intra-kernel race).
__global__ __launch_bounds__(256, 4) void gemm_kernel(const float* __restrict__ x,
                                                      const float* __restrict__ W,
                                                      const float* __restrict__ bias,
                                                      float* __restrict__ a,
                                                      int* __restrict__ rec,
                                                      int* __restrict__ acc) {
  if (blockIdx.x < 32) {
    rec[blockIdx.x * 256 + threadIdx.x] = 0;
  } else if (blockIdx.x == 32 && threadIdx.x < 4) {
    acc[threadIdx.x] = 0;
  }
  const int wave = threadIdx.x >> 6;
  const int lane = threadIdx.x & 63;
  const int p0 = blockIdx.x * 16 + wave * 4;
  const float4* __restrict__ Wr[4];
  #pragma unroll
  for (int r = 0; r < 4; ++r) Wr[r] = (const float4*)(W + (size_t)(p0 + r) * DD);
  const float4* __restrict__ x4 = (const float4*)x;
  double accd[4][4];
  #pragma unroll
  for (int r = 0; r < 4; ++r)
    #pragma unroll
    for (int b = 0; b < 4; ++b) accd[r][b] = 0.0;
  #pragma unroll 2
  for (int k = 0; k < 16; ++k) {
    const int i = lane + k * 64;
    float4 w0 = Wr[0][i];
    float4 w1 = Wr[1][i];
    float4 w2 = Wr[2][i];
    float4 w3 = Wr[3][i];
    float4 v0 = x4[i];
    float4 v1 = x4[1024 + i];
    float4 v2 = x4[2048 + i];
    float4 v3 = x4[3072 + i];
    accd[0][0] += (double)dot4(w0, v0);
    accd[0][1] += (double)dot4(w0, v1);
    accd[0][2] += (double)dot4(w0, v2);
    accd[0][3] += (double)dot4(w0, v3);
    accd[1][0] += (double)dot4(w1, v0);
    accd[1][1] += (double)dot4(w1, v1);
    accd[1][2] += (double)dot4(w1, v2);
    accd[1][3] += (double)dot4(w1, v3);
    accd[2][0] += (double)dot4(w2, v0);
    accd[2][1] += (double)dot4(w2, v1);
    accd[2][2] += (double)dot4(w2, v2);
    accd[2][3] += (double)dot4(w2, v3);
    accd[3][0] += (double)dot4(w3, v0);
    accd[3][1] += (double)dot4(w3, v1);
    accd[3][2] += (double)dot4(w3, v2);
    accd[3][3] += (double)dot4(w3, v3);
  }
  #pragma unroll
  for (int r = 0; r < 4; ++r)
    #pragma unroll
    for (int b = 0; b < 4; ++b)
      #pragma unroll
      for (int off = 32; off > 0; off >>= 1)
        accd[r][b] += __shfl_down(accd[r][b], off);
  if (lane < 4) {
    // lane r writes row p0+r (readfirstlane-free: shuffle results already in lane 0)
  }
  if (lane == 0) {
    #pragma unroll
    for (int r = 0; r < 4; ++r) {
      float bp = bias[p0 + r];
      #pragma unroll
      for (int b = 0; b < 4; ++b) a[b * PP + p0 + r] = (float)accd[r][b] + bp;
    }
  }
}

// ---------------- Kernel 2: exact 0.9-quantile via LDS histogram ----------------
// Single 1024-thr block: build 8192-bin LDS histogram of bits(|a|)>>18
// (native ds_add_u32), scan, locate buckets for ranks K_LOW/K_LOW+1, gather
// candidates in a second L2-hot pass, exact in-bucket rank select.
__global__ __launch_bounds__(1024) void thr_kernel(const float* __restrict__ a,
                                                   float* __restrict__ thr) {
  __shared__ unsigned h[NBINS];
  __shared__ unsigned scan[1024];
  __shared__ unsigned list1[LIST_CAP];
  __shared__ unsigned list2[LIST_CAP];
  __shared__ unsigned s_n1, s_n2;
  __shared__ unsigned s_b1, s_r1, s_b2, s_r2;
  __shared__ unsigned s_vlo, s_vhi;
  const int tid = threadIdx.x;
  #pragma unroll
  for (int j = 0; j < NBINS / 1024; ++j) h[tid + j * 1024] = 0u;
  if (tid == 0) { s_n1 = 0; s_n2 = 0; }
  __syncthreads();
  for (int i = tid; i < NTOT; i += 1024) {
    unsigned u = __float_as_uint(fabsf(a[i]));
    atomicAdd(&h[u >> 18], 1u);
  }
  __syncthreads();
  unsigned bins[8];
  #pragma unroll
  for (int j = 0; j < 8; ++j) bins[j] = h[tid * 8 + j];
  unsigned part = 0;
  #pragma unroll
  for (int j = 0; j < 8; ++j) part += bins[j];
  scan[tid] = part;
  __syncthreads();
  for (int off = 1; off < 1024; off <<= 1) {
    unsigned v = (tid >= off) ? scan[tid - off] : 0u;
    __syncthreads();
    scan[tid] += v;
    __syncthreads();
  }
  const unsigned incl = scan[tid];
  const unsigned excl = incl - part;
  if (excl <= (unsigned)K_LOW && (unsigned)K_LOW < incl) {
    unsigned r = (unsigned)K_LOW - excl, cum = 0;
    #pragma unroll
    for (int j = 0; j < 8; ++j) {
      if (cum + bins[j] > r) { s_b1 = tid * 8 + j; s_r1 = r - cum; break; }
      cum += bins[j];
    }
  }
  if (excl <= (unsigned)(K_LOW + 1) && (unsigned)(K_LOW + 1) < incl) {
    unsigned r = (unsigned)(K_LOW + 1) - excl, cum = 0;
    #pragma unroll
    for (int j = 0; j < 8; ++j) {
      if (cum + bins[j] > r) { s_b2 = tid * 8 + j; s_r2 = r - cum; break; }
      cum += bins[j];
    }
  }
  __syncthreads();
  const unsigned b1 = s_b1, r1 = s_r1, b2 = s_b2, r2 = s_r2;
  for (int i = tid; i < NTOT; i += 1024) {
    unsigned u = __float_as_uint(fabsf(a[i]));
    unsigned bk = u >> 18;
    if (bk == b1) {
      unsigned idx = atomicAdd(&s_n1, 1u);
      if (idx < LIST_CAP) list1[idx] = u;
    } else if (bk == b2) {
      unsigned idx = atomicAdd(&s_n2, 1u);
      if (idx < LIST_CAP) list2[idx] = u;
    }
  }
  __syncthreads();
  const unsigned m1 = min(s_n1, (unsigned)LIST_CAP);
  const unsigned m2 = min(s_n2, (unsigned)LIST_CAP);
  for (unsigned i = tid; i < m1; i += 1024) {
    unsigned ui = list1[i];
    unsigned ltc = 0, eqb = 0;
    for (unsigned j = 0; j < m1; ++j) {
      unsigned uj = list1[j];
      ltc += (uj < ui) ? 1u : 0u;
      eqb += ((uj == ui) && (j < i)) ? 1u : 0u;
    }
    unsigned rk = ltc + eqb;
    if (rk == r1) s_vlo = ui;
    if (b2 == b1 && rk == r2) s_vhi = ui;
  }
  if (b2 != b1) {
    for (unsigned i = tid; i < m2; i += 1024) {
      unsigned ui = list2[i];
      unsigned ltc = 0, eqb = 0;
      for (unsigned j = 0; j < m2; ++j) {
        unsigned uj = list2[j];
        ltc += (uj < ui) ? 1u : 0u;
        eqb += ((uj == ui) && (j < i)) ? 1u : 0u;
      }
      if (ltc + eqb == r2) s_vhi = ui;
    }
  }
  __syncthreads();
  if (tid == 0) {
    double dlo = (double)__uint_as_float(s_vlo);
    double dhi = (double)__uint_as_float(s_vhi);
    double idx = 0.9 * (double)(NTOT - 1);
    double g = idx - floor(idx);
    thr[0] = (float)(dlo + g * (dhi - dlo));
  }
}

// ---------------- Kernel 3: COO SpMV, int fixed-point LDS accum ----------------
__global__ __launch_bounds__(1024) void spmv_kernel(const float* __restrict__ vals,
                                                    const int* __restrict__ rows,
                                                    const int* __restrict__ cols,
                                                    const float* __restrict__ a,
                                                    const float* __restrict__ thr,
                                                    const float* __restrict__ sstate,
                                                    int* __restrict__ rec,
                                                    int nc) {
  __shared__ float s_state[PP];
  __shared__ int s_rec[PP];
  const int tid = threadIdx.x;
  const float t = thr[0];
  for (int i = tid; i < PP; i += 1024) {
    float a0 = a[i];
    s_state[i] = (fabsf(a0) > t) ? a0 : 0.9f * sstate[i];
    s_rec[i] = 0;
  }
  __syncthreads();
  const int n4 = nc >> 2;
  const int stride = gridDim.x * 1024;
  const float4* __restrict__ v4 = (const float4*)vals;
  const int4* __restrict__ r4 = (const int4*)rows;
  const int4* __restrict__ c4 = (const int4*)cols;
  for (int i = blockIdx.x * 1024 + tid; i < n4; i += stride) {
    float4 v = v4[i];
    int4 r = r4[i];
    int4 c = c4[i];
    atomicAdd((unsigned*)&s_rec[r.x], (unsigned)__float2int_rn(v.x * s_state[c.x] * SCALE));
    atomicAdd((unsigned*)&s_rec[r.y], (unsigned)__float2int_rn(v.y * s_state[c.y] * SCALE));
    atomicAdd((unsigned*)&s_rec[r.z], (unsigned)__float2int_rn(v.z * s_state[c.z] * SCALE));
    atomicAdd((unsigned*)&s_rec[r.w], (unsigned)__float2int_rn(v.w * s_state[c.w] * SCALE));
  }
  if (blockIdx.x == 0 && tid < (nc - (n4 << 2))) {
    int i = (n4 << 2) + tid;
    atomicAdd((unsigned*)&s_rec[rows[i]],
              (unsigned)__float2int_rn(vals[i] * s_state[cols[i]] * SCALE));
  }
  __syncthreads();
  for (int i = tid; i < PP; i += 1024)
    atomicAdd((unsigned*)&rec[i], (unsigned)s_rec[i]);
}

// ---------------- Kernel 4: GELU + fused scalars (last-block completion) ----------------
__global__ __launch_bounds__(256) void finalize_kernel(const int* __restrict__ rec,
                                                       const float* __restrict__ a,
                                                       const float* __restrict__ thr,
                                                       const float* __restrict__ sstate,
                                                       float* __restrict__ out,
                                                       int* __restrict__ acc) {
  __shared__ float wsum[4];
  __shared__ unsigned wcnt[4];
  const int p = blockIdx.x * 256 + threadIdx.x;
  const float t = thr[0];
  float r = (float)rec[p] * INV_SCALE;
  float a0 = a[p];
  float st = (fabsf(a0) > t) ? a0 : 0.9f * sstate[p];
  float v = st + 0.1f * r;
  float ns = 0.5f * v * (1.0f + erff(v * 0.70710678118654752440f));
  out[p] = ns;
  bool m = fabsf(a0) > t;
  float lsum = m ? ns : 0.0f;
  unsigned lcnt = m ? 1u : 0u;
  #pragma unroll
  for (int off = 32; off > 0; off >>= 1) {
    lsum += __shfl_down(lsum, off);
    lcnt += __shfl_down(lcnt, off);
  }
  const int lane = threadIdx.x & 63;
  const int wid = threadIdx.x >> 6;
  if (lane == 0) { wsum[wid] = lsum; wcnt[wid] = lcnt; }
  __syncthreads();
  if (threadIdx.x == 0) {
    float bsum = wsum[0] + wsum[1] + wsum[2] + wsum[3];
    unsigned bcnt = wcnt[0] + wcnt[1] + wcnt[2] + wcnt[3];
    atomicAdd((unsigned*)&acc[0], (unsigned)__float2int_rn(bsum * MSCALE));
    atomicAdd((unsigned*)&acc[1], bcnt);
    __threadfence();
    unsigned d = atomicAdd((unsigned*)&acc[2], 1u);
    if (d == (unsigned)(gridDim.x - 1)) {
      int sfix = atomicAdd(&acc[0], 0);
      int cnt = atomicAdd(&acc[1], 0);
      out[PP] = (float)cnt;
      out[PP + 1] = (cnt > 0) ? ((float)sfix * INV_MSCALE / (float)cnt) : 0.0f;
    }
  }
}

extern "C" void kernel_launch(void* const* d_in, const int* in_sizes, int n_in,
                              void* d_out, int out_size, void* d_ws, size_t ws_size,
                              hipStream_t stream) {
  const float* x      = (const float*)d_in[0];
  const float* W      = (const float*)d_in[1];
  const float* bias   = (const float*)d_in[2];
  const float* vals   = (const float*)d_in[3];
  const float* sstate = (const float*)d_in[4];
  const int*   rows   = (const int*)d_in[5];
  const int*   cols   = (const int*)d_in[6];
  const int    nc     = in_sizes[3];
  float* out = (float*)d_out;
  float* ws  = (float*)d_ws;

  float* a   = ws;                        // 32768 floats
  float* thr = ws + 32768;                // 16
  int*   rec = (int*)(ws + 32784);        // 8192 ints
  int*   acc = (int*)(ws + 32784 + PP);   // 4 ints

  gemm_kernel<<<PP / 16, 256, 0, stream>>>(x, W, bias, a, rec, acc);
  thr_kernel<<<1, 1024, 0, stream>>>(a, thr);
  spmv_kernel<<<256, 1024, 0, stream>>>(vals, rows, cols, a, thr, sstate, rec, nc);
  finalize_kernel<<<PP / 256, 256, 0, stream>>>(rec, a, thr, sstate, out, acc);
}